// Round 1
// baseline (468.182 us; speedup 1.0000x reference)
//
#include <hip/hip_runtime.h>

#define B_ 8
#define N_ 16384
#define C_ 81
#define K_ 100
#define M_ (C_ * K_)          // 8100
#define NEG_ (-1e30f)
#define NEGINF_ (-3.0e38f)
#define IOU_THR_ 0.5f

// ---------------- K1: per-(b,n) argmax over C, zero-if-bg, transpose to (B,C,N) ----
__global__ __launch_bounds__(256) void k1_transpose(const float* __restrict__ probs,
                                                    float* __restrict__ st) {
  int t = blockIdx.x * blockDim.x + threadIdx.x;   // over B*N
  if (t >= B_ * N_) return;
  int b = t >> 14;           // / N_
  int n = t & (N_ - 1);
  const float* row = probs + (size_t)t * C_;
  float best = row[0];
  int bi = 0;
  for (int c = 1; c < C_; ++c) {
    float v = row[c];
    if (v > best) { best = v; bi = c; }   // strict > keeps first occurrence (jnp.argmax)
  }
  float* outp = st + (size_t)b * C_ * N_ + n;
  if (bi == 0) {
    for (int c = 0; c < C_; ++c) outp[(size_t)c * N_] = 0.0f;
  } else {
    for (int c = 0; c < C_; ++c) outp[(size_t)c * N_] = row[c];
  }
}

// ---------------- K2: per-(b,c) exact top-100 of N scores, ties -> lower index ------
__global__ __launch_bounds__(256) void k2_topk(const float* __restrict__ st,
                                               int* __restrict__ top_idx,
                                               float* __restrict__ top_sc) {
  int bc = blockIdx.x;                    // 0..647
  const float* row = st + (size_t)bc * N_;
  __shared__ float cval[256];
  __shared__ int   cidx[256];
  __shared__ unsigned long long cmask[256];
  __shared__ float rv[4];
  __shared__ int   ri[4];
  __shared__ int   sel_s;
  int tid = threadIdx.x;
  int lane = tid & 63, wave = tid >> 6;

  // Build 256 chunk maxima (chunk = 64 contiguous elements). Wave w handles chunk 4j+w.
  for (int j = 0; j < 64; ++j) {
    int chunk = (j << 2) + wave;
    int gi = (chunk << 6) + lane;
    float v = row[gi];
    int id = gi;
    for (int off = 32; off > 0; off >>= 1) {
      float ov = __shfl_down(v, off);
      int   oi = __shfl_down(id, off);
      if (ov > v || (ov == v && oi < id)) { v = ov; id = oi; }
    }
    if (lane == 0) { cval[chunk] = v; cidx[chunk] = id; }
  }
  cmask[tid] = 0ull;
  __syncthreads();

  for (int k = 0; k < K_; ++k) {
    // block argmax over 256 chunk maxima (tie -> lower global index)
    float v = cval[tid];
    int   id = cidx[tid];
    for (int off = 32; off > 0; off >>= 1) {
      float ov = __shfl_down(v, off);
      int   oi = __shfl_down(id, off);
      if (ov > v || (ov == v && oi < id)) { v = ov; id = oi; }
    }
    if (lane == 0) { rv[wave] = v; ri[wave] = id; }
    __syncthreads();
    if (tid == 0) {
      float fv = rv[0]; int fi = ri[0];
      for (int w = 1; w < 4; ++w)
        if (rv[w] > fv || (rv[w] == fv && ri[w] < fi)) { fv = rv[w]; fi = ri[w]; }
      top_sc[bc * K_ + k] = fv;
      top_idx[bc * K_ + k] = fi;
      sel_s = fi;
    }
    __syncthreads();
    int seli = sel_s;
    int sc = seli >> 6;
    // rescan winning chunk with the selected element masked out
    if (wave == 0) {
      unsigned long long m = cmask[sc] | (1ull << (seli & 63));
      if (lane == 0) cmask[sc] = m;
      int gi = (sc << 6) + lane;
      float v2 = ((m >> lane) & 1ull) ? -1.0f : row[gi];   // scores >= 0 always
      int i2 = gi;
      for (int off = 32; off > 0; off >>= 1) {
        float ov = __shfl_down(v2, off);
        int   oi = __shfl_down(i2, off);
        if (ov > v2 || (ov == v2 && oi < i2)) { v2 = ov; i2 = oi; }
      }
      if (lane == 0) { cval[sc] = v2; cidx[sc] = i2; }
    }
    __syncthreads();
  }
}

// ---------------- K3: decode+clip selected boxes, then exact NMS keep mask ---------
__global__ __launch_bounds__(128) void k3_decode_nms(const float* __restrict__ roi,
                                                     const float* __restrict__ deltas,
                                                     const int* __restrict__ top_idx,
                                                     float* __restrict__ top_box,
                                                     int* __restrict__ keep_out) {
  int bc = blockIdx.x;
  int b = bc / C_, c = bc % C_;
  __shared__ float bx0[K_], bx1[K_], bx2[K_], bx3[K_], area[K_];
  __shared__ int keep[K_];
  int tid = threadIdx.x;
  if (tid < K_) {
    int n = top_idx[bc * K_ + tid];
    const float* a = roi + (((size_t)b << 14) + n) * 4;
    const float* d = deltas + (((size_t)b << 14) + n) * (C_ * 4) + (c << 2);
    float a0 = a[0], a1 = a[1], a2 = a[2], a3 = a[3];
    float aw = a3 - a1, ah = a2 - a0;
    float acx = a1 + 0.5f * aw, acy = a0 + 0.5f * ah;
    float d0 = d[0] * 0.1f, d1 = d[1] * 0.1f, d2 = d[2] * 0.2f, d3 = d[3] * 0.2f;
    float bw = expf(d3) * aw, bh = expf(d2) * ah;
    float bcx = d1 * aw + acx, bcy = d0 * ah + acy;
    float y1 = bcy - 0.5f * bh, x1 = bcx - 0.5f * bw;
    float y2 = bh + y1, x2 = bw + x1;
    y1 = fminf(fmaxf(y1, 0.0f), 1.0f);
    x1 = fminf(fmaxf(x1, 0.0f), 1.0f);
    y2 = fminf(fmaxf(y2, 0.0f), 1.0f);
    x2 = fminf(fmaxf(x2, 0.0f), 1.0f);
    bx0[tid] = y1; bx1[tid] = x1; bx2[tid] = y2; bx3[tid] = x2;
    area[tid] = (y2 - y1) * (x2 - x1);
    keep[tid] = 1;
  }
  __syncthreads();
  for (int i = 0; i < K_; ++i) {
    if (tid < K_ && tid > i && keep[i]) {
      float iy1 = fmaxf(bx0[i], bx0[tid]);
      float ix1 = fmaxf(bx1[i], bx1[tid]);
      float iy2 = fminf(bx2[i], bx2[tid]);
      float ix2 = fminf(bx3[i], bx3[tid]);
      float inter = fmaxf(iy2 - iy1, 0.0f) * fmaxf(ix2 - ix1, 0.0f);
      float uni = area[i] + area[tid] - inter;
      float iou = inter / fmaxf(uni, 1e-12f);
      if (iou > IOU_THR_) keep[tid] = 0;
    }
    __syncthreads();
  }
  if (tid < K_) {
    float* o = top_box + ((size_t)bc * K_ + tid) * 4;
    o[0] = bx0[tid]; o[1] = bx1[tid]; o[2] = bx2[tid]; o[3] = bx3[tid];
    keep_out[bc * K_ + tid] = keep[tid];
  }
}

// ---------------- K4: per-batch top-100 over 8100 keyed values, write outputs ------
__global__ __launch_bounds__(256) void k4_final(const float* __restrict__ top_sc,
                                                const float* __restrict__ top_box,
                                                const int* __restrict__ keep_in,
                                                float* __restrict__ out) {
  int b = blockIdx.x;
  int tid = threadIdx.x;
  __shared__ float key[8192];
  __shared__ float cval[256];
  __shared__ int   cidx[256];
  __shared__ float rv[4];
  __shared__ int   ri[4];
  __shared__ int   sel_s;
  __shared__ float selv_s;

  for (int m = tid; m < 8192; m += 256)
    key[m] = (m < M_) ? (keep_in[b * M_ + m] ? top_sc[b * M_ + m] : NEG_) : NEGINF_;
  __syncthreads();
  {
    int base = tid << 5;
    float bv = key[base];
    int bi = base;
    for (int i = 1; i < 32; ++i) {
      float v = key[base + i];
      if (v > bv) { bv = v; bi = base + i; }   // strict > -> lowest index on ties
    }
    cval[tid] = bv; cidx[tid] = bi;
  }
  __syncthreads();

  int lane = tid & 63, wave = tid >> 6;
  float* ob = out;                       // (B,K,4)
  float* oc = out + B_ * K_ * 4;         // (B,K)
  float* os = oc + B_ * K_;              // (B,K)

  for (int k = 0; k < K_; ++k) {
    float v = cval[tid];
    int   id = cidx[tid];
    for (int off = 32; off > 0; off >>= 1) {
      float ov = __shfl_down(v, off);
      int   oi = __shfl_down(id, off);
      if (ov > v || (ov == v && oi < id)) { v = ov; id = oi; }
    }
    if (lane == 0) { rv[wave] = v; ri[wave] = id; }
    __syncthreads();
    if (tid == 0) {
      float fv = rv[0]; int fi = ri[0];
      for (int w = 1; w < 4; ++w)
        if (rv[w] > fv || (rv[w] == fv && ri[w] < fi)) { fv = rv[w]; fi = ri[w]; }
      sel_s = fi; selv_s = fv;
    }
    __syncthreads();
    int mstar = sel_s;
    float kv = selv_s;
    if (tid == 0) {
      bool valid = kv > (NEG_ * 0.5f);
      const float* bp = top_box + ((size_t)b * M_ + mstar) * 4;
      float sv = top_sc[b * M_ + mstar];
      int cls = mstar / K_;
      float* obo = ob + ((size_t)b * K_ + k) * 4;
      obo[0] = valid ? bp[0] : 0.0f;
      obo[1] = valid ? bp[1] : 0.0f;
      obo[2] = valid ? bp[2] : 0.0f;
      obo[3] = valid ? bp[3] : 0.0f;
      oc[b * K_ + k] = valid ? (float)cls : 0.0f;
      os[b * K_ + k] = valid ? sv : 0.0f;
    }
    int sc = mstar >> 5;
    if (wave == 0) {
      int l5 = lane & 31;
      int gm = (sc << 5) + l5;
      float v2;
      int i2 = gm;
      if (lane < 32) {
        v2 = (gm == mstar) ? NEGINF_ : key[gm];
        if (gm == mstar) key[gm] = NEGINF_;
      } else {
        v2 = NEGINF_;
      }
      for (int off = 32; off > 0; off >>= 1) {
        float ov = __shfl_down(v2, off);
        int   oi = __shfl_down(i2, off);
        if (ov > v2 || (ov == v2 && oi < i2)) { v2 = ov; i2 = oi; }
      }
      if (lane == 0) { cval[sc] = v2; cidx[sc] = i2; }
    }
    __syncthreads();
  }
}

extern "C" void kernel_launch(void* const* d_in, const int* in_sizes, int n_in,
                              void* d_out, int out_size, void* d_ws, size_t ws_size,
                              hipStream_t stream) {
  const float* roi    = (const float*)d_in[0];   // (B,N,4)
  const float* deltas = (const float*)d_in[1];   // (B,N,C*4)
  const float* probs  = (const float*)d_in[2];   // (B,N,C)
  float* out = (float*)d_out;

  char* ws = (char*)d_ws;
  float* st = (float*)ws;                                   // B*C*N floats (42.5 MB)
  size_t off = (size_t)B_ * C_ * N_ * sizeof(float);
  int*   top_idx = (int*)(ws + off);  off += (size_t)B_ * M_ * sizeof(int);
  float* top_sc  = (float*)(ws + off); off += (size_t)B_ * M_ * sizeof(float);
  float* top_box = (float*)(ws + off); off += (size_t)B_ * M_ * 4 * sizeof(float);
  int*   keepA   = (int*)(ws + off);   off += (size_t)B_ * M_ * sizeof(int);
  (void)ws_size; (void)in_sizes; (void)n_in; (void)out_size;

  k1_transpose<<<(B_ * N_) / 256, 256, 0, stream>>>(probs, st);
  k2_topk<<<B_ * C_, 256, 0, stream>>>(st, top_idx, top_sc);
  k3_decode_nms<<<B_ * C_, 128, 0, stream>>>(roi, deltas, top_idx, top_box, keepA);
  k4_final<<<B_, 256, 0, stream>>>(top_sc, top_box, keepA, out);
}

// Round 2
// 130.186 us; speedup vs baseline: 3.5962x; 3.5962x over previous
//
#include <hip/hip_runtime.h>

#define B_ 8
#define N_ 16384
#define C_ 81
#define K_ 100
#define M_ (C_ * K_)          // 8100
#define NEG_ (-1e30f)
#define IOU_THR_ 0.5f
#define CAP_ 256

// monotone key: order of key_of(v) == order of v (all floats)
__device__ inline unsigned key_of(float v) {
  unsigned u = __float_as_uint(v);
  return u ^ ((unsigned)((int)u >> 31) | 0x80000000u);
}

// Find the bin containing the kth-largest element given hist[4096].
// Writes: *out_b = bin index, *out_g = count strictly greater than bin.
// Requires kth >= 1 and sum(hist) >= kth. Ends with __syncthreads().
__device__ inline void find_kth_bin(unsigned* hist, unsigned* scan, unsigned kth,
                                    unsigned* out_b, unsigned* out_g) {
  int tid = threadIdx.x;
  int base = tid << 4;
  unsigned local = 0;
#pragma unroll
  for (int i = 0; i < 16; ++i) local += hist[base + ((tid + i) & 15)];  // rotated: conflict-free
  scan[tid] = local;
  __syncthreads();
  for (int off = 1; off < 256; off <<= 1) {
    unsigned add = (tid + off < 256) ? scan[tid + off] : 0u;
    __syncthreads();
    scan[tid] += add;
    __syncthreads();
  }
  unsigned inclusive = scan[tid];       // sum over bins [base .. 4095]
  unsigned after = inclusive - local;   // sum over bins [base+16 .. 4095]
  if (after < kth && inclusive >= kth) {
    unsigned g = after;
    for (int b = 15; b >= 0; --b) {
      unsigned c = hist[base + b];
      if (g + c >= kth) { *out_b = (unsigned)(base + b); *out_g = g; break; }
      g += c;
    }
  }
  __syncthreads();
}

// ---------------- K1: per-(b,n) argmax over C, zero-if-bg, transpose to (B,C,N) ----
__global__ __launch_bounds__(256) void k1_transpose(const float* __restrict__ probs,
                                                    float* __restrict__ st) {
  int t = blockIdx.x * blockDim.x + threadIdx.x;   // over B*N
  if (t >= B_ * N_) return;
  int b = t >> 14;
  int n = t & (N_ - 1);
  const float* row = probs + (size_t)t * C_;
  float best = row[0];
  int bi = 0;
  for (int c = 1; c < C_; ++c) {
    float v = row[c];
    if (v > best) { best = v; bi = c; }
  }
  float* outp = st + (size_t)b * C_ * N_ + n;
  if (bi == 0) {
    for (int c = 0; c < C_; ++c) outp[(size_t)c * N_] = 0.0f;
  } else {
    for (int c = 0; c < C_; ++c) outp[(size_t)c * N_] = row[c];
  }
}

// ---------------- K2: per-(b,c) exact top-100 via 2-level radix select ------------
__global__ __launch_bounds__(256) void k2_topk(const float* __restrict__ st,
                                               int* __restrict__ top_idx,
                                               float* __restrict__ top_sc) {
  int bc = blockIdx.x;
  const float4* row4 = (const float4*)(st + (size_t)bc * N_);
  __shared__ unsigned hist[4096];
  __shared__ unsigned scan[256];
  __shared__ unsigned s_b1, s_g1, s_b2, s_g2, s_cnt;
  __shared__ float cv[CAP_];
  __shared__ int   ci[CAP_];
  int tid = threadIdx.x;

  // level-1 histogram (bits 31:20 of monotone key)
  for (int i = tid; i < 4096; i += 256) hist[i] = 0;
  if (tid == 0) s_cnt = 0;
  __syncthreads();
  for (int i = tid; i < (N_ / 4); i += 256) {
    float4 v = row4[i];
    atomicAdd(&hist[key_of(v.x) >> 20], 1u);
    atomicAdd(&hist[key_of(v.y) >> 20], 1u);
    atomicAdd(&hist[key_of(v.z) >> 20], 1u);
    atomicAdd(&hist[key_of(v.w) >> 20], 1u);
  }
  __syncthreads();
  find_kth_bin(hist, scan, K_, &s_b1, &s_g1);
  unsigned b1 = s_b1;
  unsigned need1 = K_ - s_g1;
  __syncthreads();

  // level-2 histogram (bits 19:8) over elements in bin b1
  for (int i = tid; i < 4096; i += 256) hist[i] = 0;
  __syncthreads();
  for (int i = tid; i < (N_ / 4); i += 256) {
    float4 v = row4[i];
    unsigned k0 = key_of(v.x), k1 = key_of(v.y), k2 = key_of(v.z), k3 = key_of(v.w);
    if ((k0 >> 20) == b1) atomicAdd(&hist[(k0 >> 8) & 0xFFFu], 1u);
    if ((k1 >> 20) == b1) atomicAdd(&hist[(k1 >> 8) & 0xFFFu], 1u);
    if ((k2 >> 20) == b1) atomicAdd(&hist[(k2 >> 8) & 0xFFFu], 1u);
    if ((k3 >> 20) == b1) atomicAdd(&hist[(k3 >> 8) & 0xFFFu], 1u);
  }
  __syncthreads();
  find_kth_bin(hist, scan, need1, &s_b2, &s_g2);
  unsigned t24 = (b1 << 12) | s_b2;
  __syncthreads();

  // compact candidates with key24 >= t24 (count in [100, ~110] statistically)
  for (int i = tid; i < (N_ / 4); i += 256) {
    float4 v = row4[i];
    float a[4] = {v.x, v.y, v.z, v.w};
#pragma unroll
    for (int u = 0; u < 4; ++u) {
      unsigned k = key_of(a[u]);
      if ((k >> 8) >= t24) {
        unsigned p = atomicAdd(&s_cnt, 1u);
        if (p < CAP_) { cv[p] = a[u]; ci[p] = 4 * i + u; }
      }
    }
  }
  __syncthreads();
  int cnt = (int)min(s_cnt, (unsigned)CAP_);
  // exact rank select: (value desc, index asc) -- matches lax.top_k stability
  if (tid < cnt) {
    float mv = cv[tid];
    int   mi = ci[tid];
    int rank = 0;
    for (int j = 0; j < cnt; ++j) {
      float v = cv[j]; int ji = ci[j];
      rank += (v > mv || (v == mv && ji < mi)) ? 1 : 0;
    }
    if (rank < K_) { top_sc[bc * K_ + rank] = mv; top_idx[bc * K_ + rank] = mi; }
  }
}

// ---------------- K3: decode+clip + single-wave barrier-free NMS ------------------
struct BoxR { float y1, x1, y2, x2, ar; };

__device__ inline BoxR decode_one(const float* __restrict__ roi,
                                  const float* __restrict__ deltas,
                                  int b, int c, int n) {
  float4 a = *(const float4*)(roi + (((size_t)b << 14) + n) * 4);
  float4 d = *(const float4*)(deltas + (((size_t)b << 14) + n) * (C_ * 4) + (c << 2));
  float aw = a.w - a.y, ah = a.z - a.x;
  float acx = a.y + 0.5f * aw, acy = a.x + 0.5f * ah;
  float d0 = d.x * 0.1f, d1 = d.y * 0.1f, d2 = d.z * 0.2f, d3 = d.w * 0.2f;
  float bw = expf(d3) * aw, bh = expf(d2) * ah;
  float bcx = d1 * aw + acx, bcy = d0 * ah + acy;
  float y1 = bcy - 0.5f * bh, x1 = bcx - 0.5f * bw;
  float y2 = bh + y1, x2 = bw + x1;
  BoxR r;
  r.y1 = fminf(fmaxf(y1, 0.0f), 1.0f);
  r.x1 = fminf(fmaxf(x1, 0.0f), 1.0f);
  r.y2 = fminf(fmaxf(y2, 0.0f), 1.0f);
  r.x2 = fminf(fmaxf(x2, 0.0f), 1.0f);
  r.ar = (r.y2 - r.y1) * (r.x2 - r.x1);
  return r;
}

__global__ __launch_bounds__(64) void k3_decode_nms(const float* __restrict__ roi,
                                                    const float* __restrict__ deltas,
                                                    const int* __restrict__ top_idx,
                                                    float* __restrict__ top_box,
                                                    int* __restrict__ keep_out) {
  int bc = blockIdx.x;
  int b = bc / C_, c = bc % C_;
  int tid = threadIdx.x;   // 0..63
  BoxR A = decode_one(roi, deltas, b, c, top_idx[bc * K_ + tid]);
  BoxR Bx;
  int hasB = (tid + 64 < K_);
  if (hasB) Bx = decode_one(roi, deltas, b, c, top_idx[bc * K_ + tid + 64]);
  else { Bx.y1 = Bx.x1 = Bx.y2 = Bx.x2 = Bx.ar = 0.0f; }
  int ka = 1, kb = hasB;

  for (int i = 0; i < K_; ++i) {
    int src = i & 63;
    bool hi = (i >= 64);
    float iy1 = __shfl(hi ? Bx.y1 : A.y1, src);
    float ix1 = __shfl(hi ? Bx.x1 : A.x1, src);
    float iy2 = __shfl(hi ? Bx.y2 : A.y2, src);
    float ix2 = __shfl(hi ? Bx.x2 : A.x2, src);
    float iar = __shfl(hi ? Bx.ar : A.ar, src);
    int   ki  = __shfl(hi ? kb : ka, src);
    if (ki) {
      if (ka && tid > i) {
        float yy1 = fmaxf(iy1, A.y1), xx1 = fmaxf(ix1, A.x1);
        float yy2 = fminf(iy2, A.y2), xx2 = fminf(ix2, A.x2);
        float inter = fmaxf(yy2 - yy1, 0.0f) * fmaxf(xx2 - xx1, 0.0f);
        float uni = iar + A.ar - inter;
        float iou = inter / fmaxf(uni, 1e-12f);
        if (iou > IOU_THR_) ka = 0;
      }
      if (kb && (tid + 64) > i) {
        float yy1 = fmaxf(iy1, Bx.y1), xx1 = fmaxf(ix1, Bx.x1);
        float yy2 = fminf(iy2, Bx.y2), xx2 = fminf(ix2, Bx.x2);
        float inter = fmaxf(yy2 - yy1, 0.0f) * fmaxf(xx2 - xx1, 0.0f);
        float uni = iar + Bx.ar - inter;
        float iou = inter / fmaxf(uni, 1e-12f);
        if (iou > IOU_THR_) kb = 0;
      }
    }
  }
  {
    float4 o = make_float4(A.y1, A.x1, A.y2, A.x2);
    *(float4*)(top_box + ((size_t)bc * K_ + tid) * 4) = o;
    keep_out[bc * K_ + tid] = ka;
  }
  if (hasB) {
    float4 o = make_float4(Bx.y1, Bx.x1, Bx.y2, Bx.x2);
    *(float4*)(top_box + ((size_t)bc * K_ + tid + 64) * 4) = o;
    keep_out[bc * K_ + tid + 64] = kb;
  }
}

// ---------------- K4: per-batch exact top-100 over 8100 keyed values --------------
__global__ __launch_bounds__(256) void k4_final(const float* __restrict__ top_sc,
                                                const float* __restrict__ top_box,
                                                const int* __restrict__ keep_in,
                                                float* __restrict__ out) {
  int b = blockIdx.x;
  int tid = threadIdx.x;
  __shared__ float keyed[M_];
  __shared__ unsigned hist[4096];
  __shared__ unsigned scan[256];
  __shared__ unsigned s_b1, s_g1, s_b2, s_g2, s_cnt;
  __shared__ float cv[CAP_];
  __shared__ int   ci[CAP_];
  __shared__ int   sel_m[K_];
  __shared__ float sel_v[K_];

  for (int m = tid; m < M_; m += 256)
    keyed[m] = keep_in[b * M_ + m] ? top_sc[b * M_ + m] : NEG_;
  for (int i = tid; i < 4096; i += 256) hist[i] = 0;
  if (tid == 0) s_cnt = 0;
  __syncthreads();
  for (int m = tid; m < M_; m += 256) atomicAdd(&hist[key_of(keyed[m]) >> 20], 1u);
  __syncthreads();
  find_kth_bin(hist, scan, K_, &s_b1, &s_g1);
  unsigned b1 = s_b1;
  unsigned need1 = K_ - s_g1;
  __syncthreads();
  for (int i = tid; i < 4096; i += 256) hist[i] = 0;
  __syncthreads();
  for (int m = tid; m < M_; m += 256) {
    unsigned k = key_of(keyed[m]);
    if ((k >> 20) == b1) atomicAdd(&hist[(k >> 8) & 0xFFFu], 1u);
  }
  __syncthreads();
  find_kth_bin(hist, scan, need1, &s_b2, &s_g2);
  unsigned t24 = (b1 << 12) | s_b2;
  __syncthreads();
  for (int m = tid; m < M_; m += 256) {
    float v = keyed[m];
    unsigned k = key_of(v);
    if ((k >> 8) >= t24) {
      unsigned p = atomicAdd(&s_cnt, 1u);
      if (p < CAP_) { cv[p] = v; ci[p] = m; }
    }
  }
  __syncthreads();
  int cnt = (int)min(s_cnt, (unsigned)CAP_);
  if (tid < cnt) {
    float mv = cv[tid];
    int   mi = ci[tid];
    int rank = 0;
    for (int j = 0; j < cnt; ++j) {
      float v = cv[j]; int ji = ci[j];
      rank += (v > mv || (v == mv && ji < mi)) ? 1 : 0;
    }
    if (rank < K_) { sel_m[rank] = mi; sel_v[rank] = mv; }
  }
  __syncthreads();

  float* ob = out;                 // (B,K,4)
  float* oc = out + B_ * K_ * 4;   // (B,K)
  float* os = oc + B_ * K_;        // (B,K)
  if (tid < K_) {
    int m = sel_m[tid];
    float kv = sel_v[tid];
    bool valid = kv > (NEG_ * 0.5f);
    float4 bb = *(const float4*)(top_box + ((size_t)b * M_ + m) * 4);
    float sv = top_sc[b * M_ + m];
    float cls = (float)(m / K_);
    float4 o = valid ? bb : make_float4(0.f, 0.f, 0.f, 0.f);
    *(float4*)(ob + ((size_t)b * K_ + tid) * 4) = o;
    oc[b * K_ + tid] = valid ? cls : 0.0f;
    os[b * K_ + tid] = valid ? sv : 0.0f;
  }
}

extern "C" void kernel_launch(void* const* d_in, const int* in_sizes, int n_in,
                              void* d_out, int out_size, void* d_ws, size_t ws_size,
                              hipStream_t stream) {
  const float* roi    = (const float*)d_in[0];   // (B,N,4)
  const float* deltas = (const float*)d_in[1];   // (B,N,C*4)
  const float* probs  = (const float*)d_in[2];   // (B,N,C)
  float* out = (float*)d_out;

  char* ws = (char*)d_ws;
  float* st = (float*)ws;                                    // B*C*N floats
  size_t off = (size_t)B_ * C_ * N_ * sizeof(float);
  int*   top_idx = (int*)(ws + off);   off += (size_t)B_ * M_ * sizeof(int);
  float* top_sc  = (float*)(ws + off); off += (size_t)B_ * M_ * sizeof(float);
  float* top_box = (float*)(ws + off); off += (size_t)B_ * M_ * 4 * sizeof(float);
  int*   keepA   = (int*)(ws + off);   off += (size_t)B_ * M_ * sizeof(int);
  (void)ws_size; (void)in_sizes; (void)n_in; (void)out_size;

  k1_transpose<<<(B_ * N_) / 256, 256, 0, stream>>>(probs, st);
  k2_topk<<<B_ * C_, 256, 0, stream>>>(st, top_idx, top_sc);
  k3_decode_nms<<<B_ * C_, 64, 0, stream>>>(roi, deltas, top_idx, top_box, keepA);
  k4_final<<<B_, 256, 0, stream>>>(top_sc, top_box, keepA, out);
}